// Round 2
// baseline (445.932 us; speedup 1.0000x reference)
//
#include <hip/hip_runtime.h>
#include <hip/hip_bf16.h>
#include <math.h>

#define TOKENS 16384
#define DIM 4096
#define NEXP 64
#define TOPK 8
#define FILTER_R 0.62f
#define LOAD_LR 0.001f

#define TM 8            // tokens per wave
#define WAVES 4         // waves per block -> 32 tokens/block, 512 blocks

// ---------------------------------------------------------------------------
// ws layout: [0, DIM*NEXP*4) = Wt4 transposed weights (1 MB)
//            [DIM*NEXP*4, +256) = histogram (64 ints)
// ---------------------------------------------------------------------------

// Transpose W[E][K] row-major into Wt4: element (k,e) at ((k>>2)*256 + e*4 + (k&3))
// so a wave (lane=expert) loads float4 = k..k+3 for its expert, 1KB coalesced.
__global__ void wt_transpose_kernel(const float* __restrict__ W,
                                    float* __restrict__ wt4,
                                    int* __restrict__ hist) {
    int tid = blockIdx.x * blockDim.x + threadIdx.x;   // 0 .. DIM*NEXP-1
    if (blockIdx.x == 0 && threadIdx.x < NEXP) hist[threadIdx.x] = 0;
    int e = tid >> 12;        // / DIM
    int k = tid & (DIM - 1);
    float v = W[tid];
    wt4[((k >> 2) << 8) + (e << 2) + (k & 3)] = v;
}

__global__ __launch_bounds__(256) void router_kernel(
    const float* __restrict__ x,
    const float* __restrict__ b,
    const float* __restrict__ bi,
    const float* __restrict__ rand_u,
    const float4* __restrict__ wt4,
    float* __restrict__ out,          // [0,131072) router_output, [131072,262144) indices-as-float
    int* __restrict__ hist_g) {
    __shared__ int lds_hist[NEXP];

    const int lane = threadIdx.x & 63;
    const int wave = __builtin_amdgcn_readfirstlane(threadIdx.x >> 6);
    if (threadIdx.x < NEXP) lds_hist[threadIdx.x] = 0;
    __syncthreads();

    const int t0 = blockIdx.x * (TM * WAVES) + wave * TM;

    // fp64 accumulators: double(x)*double(w) products are EXACT (24+24 <= 53
    // mantissa bits); f64 addition error over 4096 terms ~1e-14 -> top-k order
    // matches the true (f64 reference) ordering, unlike fp32 (~4e-6 error,
    // which caused the R1 index flips).
    double acc0[TM], acc1[TM];
#pragma unroll
    for (int t = 0; t < TM; ++t) { acc0[t] = 0.0; acc1[t] = 0.0; }

    const float4* xrow[TM];
#pragma unroll
    for (int t = 0; t < TM; ++t)
        xrow[t] = (const float4*)(x + (size_t)(t0 + t) * DIM);

#pragma unroll 2
    for (int k4 = 0; k4 < DIM / 4; ++k4) {
        float4 wv = wt4[k4 * 64 + lane];
        const double w0 = (double)wv.x, w1 = (double)wv.y;
        const double w2 = (double)wv.z, w3 = (double)wv.w;
#pragma unroll
        for (int t = 0; t < TM; ++t) {
            float4 xv = xrow[t][k4];          // wave-uniform address
            acc0[t] = fma((double)xv.x, w0, acc0[t]);
            acc1[t] = fma((double)xv.y, w1, acc1[t]);
            acc0[t] = fma((double)xv.z, w2, acc0[t]);
            acc1[t] = fma((double)xv.w, w3, acc1[t]);
        }
    }

    const double b_lane  = (double)b[lane];
    const double bi_lane = (double)bi[lane];

    for (int t = 0; t < TM; ++t) {
        // unbiased logit for (token t, expert=lane), effectively exact
        const double vub = (acc0[t] + acc1[t]) + b_lane;
        const float  vubf = (float)vub;
        double cur = vub + bi_lane;           // biased logit for selection

        float out_logit = -INFINITY;
        int   out_idx   = 0;

#pragma unroll
        for (int j = 0; j < TOPK; ++j) {
            // wave argmax over (cur, lane); ties -> lower index (lax.top_k stable)
            double bv = cur;
            int    bidx = lane;
#pragma unroll
            for (int s = 1; s < 64; s <<= 1) {
                double ov = __shfl_xor(bv, s, 64);
                int    oi = __shfl_xor(bidx, s, 64);
                bool take = (ov > bv) || (ov == bv && oi < bidx);
                if (take) { bv = ov; bidx = oi; }
            }
            // bidx is wave-uniform winner; fetch its UNBIASED logit (f32 is
            // plenty for the softmax output, threshold ~2%)
            float wub = __shfl(vubf, bidx, 64);
            if (lane == j) { out_logit = wub; out_idx = bidx; }
            if (lane == bidx) cur = -INFINITY;
        }

        // softmax over the 8 selected (lanes 0..7 hold them); masks 1,2,4 stay in 8-groups
        float sv = (lane < TOPK) ? out_logit : -INFINITY;
        float m = sv;
        m = fmaxf(m, __shfl_xor(m, 1, 64));
        m = fmaxf(m, __shfl_xor(m, 2, 64));
        m = fmaxf(m, __shfl_xor(m, 4, 64));
        float e = (lane < TOPK) ? expf(sv - m) : 0.f;
        float ssum = e;
        ssum += __shfl_xor(ssum, 1, 64);
        ssum += __shfl_xor(ssum, 2, 64);
        ssum += __shfl_xor(ssum, 4, 64);

        const int tt = t0 + t;
        if (lane < TOPK) {
            float p = e / ssum;
            float r = rand_u[tt * TOPK + lane];
            out[tt * TOPK + lane] = (r > FILTER_R) ? p : 0.f;
            out[TOKENS * TOPK + tt * TOPK + lane] = (float)out_idx;
            atomicAdd(&lds_hist[out_idx], 1);
        }
    }

    __syncthreads();
    if (threadIdx.x < NEXP) atomicAdd(&hist_g[threadIdx.x], lds_hist[threadIdx.x]);
}

__global__ void bias_update_kernel(const float* __restrict__ bi,
                                   const int* __restrict__ hist,
                                   float* __restrict__ out_bi) {
    int e = threadIdx.x;
    float c_avg = (float)TOKENS / (float)NEXP;     // 256
    float e_i = c_avg - (float)hist[e];
    float s = (e_i > 0.f) ? 1.f : ((e_i < 0.f) ? -1.f : 0.f);
    out_bi[e] = bi[e] + LOAD_LR * s;
}

extern "C" void kernel_launch(void* const* d_in, const int* in_sizes, int n_in,
                              void* d_out, int out_size, void* d_ws, size_t ws_size,
                              hipStream_t stream) {
    const float* x      = (const float*)d_in[0];
    const float* W      = (const float*)d_in[1];
    const float* b      = (const float*)d_in[2];
    const float* bi     = (const float*)d_in[3];
    const float* rand_u = (const float*)d_in[4];

    float* out  = (float*)d_out;
    float* wt4  = (float*)d_ws;
    int*   hist = (int*)((char*)d_ws + (size_t)DIM * NEXP * sizeof(float));

    // 1) transpose W for coalesced lane=expert loads; also zeroes histogram
    wt_transpose_kernel<<<(DIM * NEXP) / 256, 256, 0, stream>>>(W, wt4, hist);

    // 2) fused logits + top-k + softmax + mask + histogram (f64 accumulation)
    router_kernel<<<TOKENS / (TM * WAVES), 256, 0, stream>>>(
        x, b, bi, rand_u, (const float4*)wt4, out, hist);

    // 3) load-balance bias update -> out[262144..262208)
    bias_update_kernel<<<1, NEXP, 0, stream>>>(bi, hist, out + 2 * TOKENS * TOPK);
}